// Round 6
// baseline (671.188 us; speedup 1.0000x reference)
//
#include <hip/hip_runtime.h>
#include <cstdint>
#include <cstddef>

#define D_HEAD   64
#define NHEAD    16
#define DMODEL   1024
#define SLEN     2048
#define BSZ      4
#define MROWS    (SLEN*BSZ)            // 8192
#define NQKVB    (NHEAD*(3*D_HEAD+1))  // 3088
#define NQPAD    3200                  // padded to 25*128 for the 128-tile GEMM
#define EPSV     1e-5f
#define SCALEV   0.125f                // 1/sqrt(64)
#define GQ       4                     // recurrence lookahead group
#define NGRP     (SLEN/GQ)             // 512

typedef short bf16x8 __attribute__((ext_vector_type(8)));
typedef float f32x4  __attribute__((ext_vector_type(4)));

__device__ __forceinline__ unsigned short f2bf(float f){
  unsigned int u = __float_as_uint(f);
  u = (u + 0x7fffu + ((u >> 16) & 1u)) >> 16;   // RNE
  return (unsigned short)u;
}
__device__ __forceinline__ float bf2f(unsigned short s){
  return __uint_as_float(((unsigned int)s) << 16);
}

__device__ __forceinline__ void gload_lds16(const unsigned short* g, unsigned short* l){
  __builtin_amdgcn_global_load_lds((const __attribute__((address_space(1))) void*)g,
                                   (__attribute__((address_space(3))) void*)l, 16, 0, 0);
}

// ------------------------------------------------------------------ cast
__global__ void cast_bf16_kernel(const float* __restrict__ src,
                                 unsigned short* __restrict__ dst, int n4){
  int stride = gridDim.x * blockDim.x;
  for (int i = blockIdx.x*blockDim.x + threadIdx.x; i < n4; i += stride){
    float4 f = ((const float4*)src)[i];
    ushort4 u;
    u.x = f2bf(f.x); u.y = f2bf(f.y); u.z = f2bf(f.z); u.w = f2bf(f.w);
    ((ushort4*)dst)[i] = u;
  }
}

// ------------------------------------------------------------------ GEMM (NT), m97 structure
template<bool OUT_BF16>
__global__ __launch_bounds__(256) void gemm_big_kernel(
    const unsigned short* __restrict__ A, const unsigned short* __restrict__ B,
    void* __restrict__ C, int M, int N, int K){
  __shared__ __align__(16) unsigned short sA[128*32];
  __shared__ __align__(16) unsigned short sB[128*32];
  int m0 = blockIdx.x * 128, n0 = blockIdx.y * 128;
  int tid = threadIdx.x;
  int wv = tid >> 6, ln = tid & 63;
  int lm = ln & 15, quad = ln >> 4;
  int wm = (wv >> 1) * 64, wn = (wv & 1) * 64;
  f32x4 acc[4][4] = {};

  for (int kt = 0; kt < K; kt += 32){
    __syncthreads();
    #pragma unroll
    for (int it = 0; it < 2; ++it){
      int s = wv*128 + it*64 + ln;          // 0..511
      int row = s >> 2, sg = s & 3;
      gload_lds16(A + (size_t)(m0+row)*K + kt + sg*8, sA + (size_t)(wv*128 + it*64)*8);
      gload_lds16(B + (size_t)(n0+row)*K + kt + sg*8, sB + (size_t)(wv*128 + it*64)*8);
    }
    __syncthreads();
    bf16x8 af[4], bfr[4];
    #pragma unroll
    for (int i = 0; i < 4; ++i){
      af[i]  = *(const bf16x8*)(sA + ((wm + i*16 + lm)*32 + quad*8));
      bfr[i] = *(const bf16x8*)(sB + ((wn + i*16 + lm)*32 + quad*8));
    }
    #pragma unroll
    for (int mi = 0; mi < 4; ++mi)
      #pragma unroll
      for (int ni = 0; ni < 4; ++ni)
        acc[mi][ni] = __builtin_amdgcn_mfma_f32_16x16x32_bf16(af[mi], bfr[ni], acc[mi][ni], 0, 0, 0);
  }

  #pragma unroll
  for (int mi = 0; mi < 4; ++mi){
    int rowm = m0 + wm + mi*16 + quad*4;
    #pragma unroll
    for (int ni = 0; ni < 4; ++ni){
      int col = n0 + wn + ni*16 + lm;
      size_t cb = (size_t)rowm * N + col;
      #pragma unroll
      for (int rr = 0; rr < 4; ++rr){
        float v = acc[mi][ni][rr];
        if (OUT_BF16) ((unsigned short*)C)[cb + (size_t)rr*N] = f2bf(v);
        else          ((float*)C)[cb + (size_t)rr*N] = v;
      }
    }
  }
}

// ------------------------------------------------------------------ preprocess
__global__ __launch_bounds__(256) void prep_kernel(
    const unsigned short* __restrict__ qkvb,
    float* __restrict__ qb, float* __restrict__ kb, float* __restrict__ vb,
    float4* __restrict__ scal){
  int gid = blockIdx.x*4 + (threadIdx.x >> 6);   // m*16 + h
  int ln  = threadIdx.x & 63;
  int m = gid >> 4, h = gid & 15;
  size_t rb = (size_t)m * NQPAD + (size_t)h * 193;
  float qr = bf2f(qkvb[rb + ln]);
  float kr = bf2f(qkvb[rb + 64 + ln]);
  float vr = bf2f(qkvb[rb + 128 + ln]);
  float br = bf2f(qkvb[rb + 192]);
  float q1 = qr > 0.f ? qr + 1.f : __expf(qr);   // elu(x)+1
  float k1 = kr > 0.f ? kr + 1.f : __expf(kr);
  float sq = q1, sk = k1;
  #pragma unroll
  for (int off = 1; off < 64; off <<= 1){
    sq += __shfl_xor(sq, off, 64);
    sk += __shfl_xor(sk, off, 64);
  }
  float qn = q1 / sq, kn = k1 / sk;
  int b = m & 3, t = m >> 2;
  int bh = b*16 + h;
  size_t o = ((size_t)bh*SLEN + t)*64 + ln;
  qb[o] = qn; kb[o] = kn; vb[o] = vr;
  if (ln == 0){
    float sb = 1.f / (1.f + __expf(-br));
    scal[(size_t)bh*SLEN + t] = make_float4(0.f, 0.f, 0.f, sb);
  }
}

// ------------------------------------------------------------------ segmented cumsum over l
#define NSEG 16
#define SEGL (SLEN/NSEG)   // 128
__global__ __launch_bounds__(64) void segsum_kernel(
    const float* __restrict__ kb, float* __restrict__ S){
  int bh = blockIdx.x, seg = blockIdx.y, ln = threadIdx.x;
  size_t base = ((size_t)bh*SLEN + (size_t)seg*SEGL)*64 + ln;
  float s = 0.f;
  #pragma unroll 4
  for (int t = 0; t < SEGL; ++t) s += kb[base + (size_t)t*64];
  S[((size_t)bh*NSEG + seg)*64 + ln] = s;
}
__global__ __launch_bounds__(64) void scan_kernel(
    const float* __restrict__ kb, const float* __restrict__ S,
    float* __restrict__ Ab){
  int bh = blockIdx.x, seg = blockIdx.y, ln = threadIdx.x;
  float acc = 0.f;
  for (int s = 0; s < seg; ++s) acc += S[((size_t)bh*NSEG + s)*64 + ln];
  size_t base = ((size_t)bh*SLEN + (size_t)seg*SEGL)*64 + ln;
  #pragma unroll 4
  for (int t = 0; t < SEGL; ++t){
    acc += kb[base + (size_t)t*64];
    Ab[base + (size_t)t*64] = acc;
  }
}

// ------------------------------------------------------------------ denominators
// scal = {beta*kd, <kf,q>, SCALEV/(den+eps), -}; kb <- kf = kn/(kd+eps)
__global__ __launch_bounds__(256) void kden_kernel(
    const float* __restrict__ Ab, float* __restrict__ kb,
    const float* __restrict__ qb, float4* __restrict__ scal){
  int gid = blockIdx.x*4 + (threadIdx.x >> 6);   // bh*2048 + t
  int ln  = threadIdx.x & 63;
  int t = gid & (SLEN-1);
  size_t o = (size_t)gid*64 + ln;
  float a = Ab[o], kn = kb[o], qn = qb[o];
  float d0 = (a - kn)*kn, d1 = a*qn, d2 = kn*qn;
  #pragma unroll
  for (int off = 1; off < 64; off <<= 1){
    d0 += __shfl_xor(d0, off, 64);
    d1 += __shfl_xor(d1, off, 64);
    d2 += __shfl_xor(d2, off, 64);
  }
  float kd  = (t == 0) ? 1.f : d0;
  float inv = 1.f / (kd + EPSV);
  kb[o] = kn * inv;
  if (ln == 0){
    float4 s = scal[gid];
    scal[gid] = make_float4(s.w * kd, d2 * inv, SCALEV/(d1 + EPSV), 0.f);
  }
}

// ------------------------------------------------------------------ DPP helpers
template<int CTRL>
__device__ __forceinline__ float dpp_add(float x){
  return x + __int_as_float(__builtin_amdgcn_mov_dpp(__float_as_int(x), CTRL, 0xF, 0xF, true));
}
__device__ __forceinline__ float red16(float x){       // allreduce within 16-lane row
  x = dpp_add<0xB1>(x);    // quad_perm [1,0,3,2]
  x = dpp_add<0x4E>(x);    // quad_perm [2,3,0,1]
  x = dpp_add<0x124>(x);   // row_ror:4
  x = dpp_add<0x128>(x);   // row_ror:8
  return x;
}
__device__ __forceinline__ float red64_tail(float x){  // wave sum, valid in lane 63
  x = dpp_add<0x111>(x);   // row_shr:1
  x = dpp_add<0x112>(x);   // row_shr:2
  x = dpp_add<0x114>(x);   // row_shr:4
  x = dpp_add<0x118>(x);   // row_shr:8
  x = dpp_add<0x142>(x);   // row_bcast:15
  x = dpp_add<0x143>(x);   // row_bcast:31
  return x;
}

// ------------------------------------------------------------------ pairwise dots for rank-4 lookahead
// one wave per (bh, group T of 4 steps); lane = d. Writes, per group, 3 float4:
// P0={kk01,kk02,kk03,kk12} P1={kk13,kk23,kq01,kq02} P2={kq03,kq12,kq13,kq23}
// (kk_ij = kf_i·kf_j, kq_ij = kf_i·q_j within the group; slot stride 4 float4)
__global__ __launch_bounds__(256) void pairdot_kernel(
    const float* __restrict__ kb, const float* __restrict__ qb,
    float4* __restrict__ pair){
  int gid = blockIdx.x*4 + (threadIdx.x >> 6);   // bh*NGRP + T
  int ln  = threadIdx.x & 63;
  size_t base = (size_t)gid*256 + ln;
  float k0 = kb[base], k1 = kb[base+64], k2 = kb[base+128], k3 = kb[base+192];
  float q1 = qb[base+64], q2 = qb[base+128], q3 = qb[base+192];
  float r0  = red64_tail(k0*k1);
  float r1  = red64_tail(k0*k2);
  float r2  = red64_tail(k0*k3);
  float r3  = red64_tail(k1*k2);
  float r4  = red64_tail(k1*k3);
  float r5  = red64_tail(k2*k3);
  float r6  = red64_tail(k0*q1);
  float r7  = red64_tail(k0*q2);
  float r8  = red64_tail(k0*q3);
  float r9  = red64_tail(k1*q2);
  float r10 = red64_tail(k1*q3);
  float r11 = red64_tail(k2*q3);
  if (ln == 63){
    pair[(size_t)gid*4 + 0] = make_float4(r0, r1, r2, r3);
    pair[(size_t)gid*4 + 1] = make_float4(r4, r5, r6, r7);
    pair[(size_t)gid*4 + 2] = make_float4(r8, r9, r10, r11);
  }
}

// ------------------------------------------------------------------ delta-rule recurrence, rank-4 groups
// grid (64 bh, 16 row-groups), 64 threads = 4 rows x 16 col-groups.
// lane: r = grp*4 + (ln>>4), owns W[r][c*4..c*4+4), c = ln&15.
#define DOT4(a,b) ((a).x*(b).x + (a).y*(b).y + (a).z*(b).z + (a).w*(b).w)

__global__ __launch_bounds__(64) void recur_kernel(
    const float* __restrict__ kb, const float* __restrict__ qb,
    const float* __restrict__ vb, const float4* __restrict__ scal,
    const float4* __restrict__ pair, unsigned short* __restrict__ lo){
  int bh = blockIdx.x;
  int grp = blockIdx.y;
  int ln = threadIdx.x;
  int c  = ln & 15;
  int r  = grp*4 + (ln >> 4);
  size_t base = (size_t)bh * SLEN * 64;
  const float4* kp = (const float4*)(kb + base) + c;
  const float4* qp = (const float4*)(qb + base) + c;
  const float*  vp = vb + base + r;
  const float4* sp = scal + (size_t)bh * SLEN;
  const float4* pp = pair + (size_t)bh * NGRP * 4;
  // lane c (<4) stores out for step T*4+c of its row r
  unsigned short* lopc = lo + (size_t)(bh>>4)*DMODEL + (size_t)(bh&15)*64 + r
                            + (size_t)c*(BSZ*DMODEL);

  float4 W = {0,0,0,0};
  float4 kB[2][4], qB[2][4], scB[2][3+1], prB[2][3];
  float  vB[2][4];

  // initial prefetch of group 0 into buffer 0
  #pragma unroll
  for (int i = 0; i < 4; ++i){
    kB[0][i] = kp[i*16];
    qB[0][i] = qp[i*16];
    vB[0][i] = vp[(size_t)i*64];
    scB[0][i] = sp[i];
  }
  #pragma unroll
  for (int i = 0; i < 3; ++i) prB[0][i] = pp[i];

  for (int T2 = 0; T2 < NGRP; T2 += 2){
    #pragma unroll
    for (int ph = 0; ph < 2; ++ph){
      const int b = ph, nb = ph ^ 1;
      int T = T2 + ph;
      int tn = (T + 1) * GQ;               // next group's first step (may overrun into pad)
      // prefetch next group
      #pragma unroll
      for (int i = 0; i < 4; ++i){
        kB[nb][i] = kp[(tn+i)*16];
        qB[nb][i] = qp[(tn+i)*16];
        vB[nb][i] = vp[(size_t)(tn+i)*64];
        scB[nb][i] = sp[tn+i];
      }
      #pragma unroll
      for (int i = 0; i < 3; ++i) prB[nb][i] = pp[(T+1)*4 + i];

      float4 k0 = kB[b][0], k1 = kB[b][1], k2 = kB[b][2], k3 = kB[b][3];
      float4 q0 = qB[b][0], q1 = qB[b][1], q2 = qB[b][2], q3 = qB[b][3];
      float4 s0 = scB[b][0], s1 = scB[b][1], s2 = scB[b][2], s3 = scB[b][3];
      float4 P0 = prB[b][0], P1 = prB[b][1], P2 = prB[b][2];
      float v0 = vB[b][0], v1 = vB[b][1], v2 = vB[b][2], v3 = vB[b][3];

      // 8 independent dots + 8 independent reduce trees (deep ILP)
      float m0 = red16(DOT4(W,k0));
      float m1 = red16(DOT4(W,k1));
      float m2 = red16(DOT4(W,k2));
      float m3 = red16(DOT4(W,k3));
      float p0 = red16(DOT4(W,q0));
      float p1 = red16(DOT4(W,q1));
      float p2 = red16(DOT4(W,q2));
      float p3 = red16(DOT4(W,q3));

      // forward substitution (scalar chain)
      float d0 = s0.x * (v0 - m0);
      float d1 = s1.x * (v1 - m1 - P0.x*d0);
      float d2 = s2.x * (v2 - m2 - P0.y*d0 - P0.w*d1);
      float d3 = s3.x * (v3 - m3 - P0.z*d0 - P1.x*d1 - P1.y*d2);

      float o0 = (p0 + s0.y*d0) * s0.z;
      float o1 = (p1 + P1.z*d0 + s1.y*d1) * s1.z;
      float o2 = (p2 + P1.w*d0 + P2.y*d1 + s2.y*d2) * s2.z;
      float o3 = (p3 + P2.x*d0 + P2.z*d1 + P2.w*d2 + s3.y*d3) * s3.z;

      // rank-4 W update
      W.x += d0*k0.x + d1*k1.x + d2*k2.x + d3*k3.x;
      W.y += d0*k0.y + d1*k1.y + d2*k2.y + d3*k3.y;
      W.z += d0*k0.z + d1*k1.z + d2*k2.z + d3*k3.z;
      W.w += d0*k0.w + d1*k1.w + d2*k2.w + d3*k3.w;

      float mo = (c == 0) ? o0 : (c == 1) ? o1 : (c == 2) ? o2 : o3;
      if (c < 4)
        lopc[(size_t)(T*GQ)*(BSZ*DMODEL)] = f2bf(mo);
    }
  }
}

// ------------------------------------------------------------------ residual + layernorm
__global__ __launch_bounds__(256) void ln_kernel(
    const float* __restrict__ hin, const float* __restrict__ attn,
    const float* __restrict__ g, const float* __restrict__ bta,
    float* __restrict__ out){
  int row = blockIdx.x, tid = threadIdx.x;
  size_t rb = (size_t)row * DMODEL;
  float4 hv = ((const float4*)(hin + rb))[tid];
  float4 av = ((const float4*)(attn + rb))[tid];
  float4 x;
  x.x = hv.x + av.x; x.y = hv.y + av.y; x.z = hv.z + av.z; x.w = hv.w + av.w;
  float s  = x.x + x.y + x.z + x.w;
  float ss = x.x*x.x + x.y*x.y + x.z*x.z + x.w*x.w;
  #pragma unroll
  for (int off = 1; off < 64; off <<= 1){
    s  += __shfl_xor(s , off, 64);
    ss += __shfl_xor(ss, off, 64);
  }
  __shared__ float ls[4], lq[4];
  int wv = tid >> 6, ln = tid & 63;
  if (ln == 0){ ls[wv] = s; lq[wv] = ss; }
  __syncthreads();
  s  = ls[0] + ls[1] + ls[2] + ls[3];
  ss = lq[0] + lq[1] + lq[2] + lq[3];
  float mu  = s * (1.f/DMODEL);
  float var = ss * (1.f/DMODEL) - mu*mu;
  float rstd = rsqrtf(var + EPSV);
  float4 gv = ((const float4*)g)[tid], bv = ((const float4*)bta)[tid];
  float4 o;
  o.x = (x.x-mu)*rstd*gv.x + bv.x;
  o.y = (x.y-mu)*rstd*gv.y + bv.y;
  o.z = (x.z-mu)*rstd*gv.z + bv.z;
  o.w = (x.w-mu)*rstd*gv.w + bv.w;
  ((float4*)(out + rb))[tid] = o;
}

// ------------------------------------------------------------------ launch
extern "C" void kernel_launch(void* const* d_in, const int* in_sizes, int n_in,
                              void* d_out, int out_size, void* d_ws, size_t ws_size,
                              hipStream_t stream){
  const float* h     = (const float*)d_in[0];
  const float* wqkvb = (const float*)d_in[1];
  const float* wo    = (const float*)d_in[2];
  const float* lng   = (const float*)d_in[3];
  const float* lnb   = (const float*)d_in[4];
  float* out = (float*)d_out;

  char* w = (char*)d_ws;
  auto take = [&](size_t bytes)->char*{
    char* p = w; w += (bytes + 255) & ~(size_t)255; return p;
  };
  unsigned short* h_bf    = (unsigned short*)take((size_t)MROWS*DMODEL*2);
  unsigned short* wq_bf   = (unsigned short*)take((size_t)NQPAD*DMODEL*2);   // padded rows
  unsigned short* wo_bf   = (unsigned short*)take((size_t)DMODEL*DMODEL*2);
  unsigned short* qkvb_bf = (unsigned short*)take((size_t)MROWS*NQPAD*2);    // padded cols
  float* qb   = (float*)take((size_t)MROWS*DMODEL*4 + 4096);  // +pad for prefetch overrun
  float* kb   = (float*)take((size_t)MROWS*DMODEL*4 + 4096);
  float* vb   = (float*)take((size_t)MROWS*DMODEL*4 + 4096);
  float* Ab   = (float*)take((size_t)MROWS*DMODEL*4);   // reused as attn after kden
  float4* scal = (float4*)take((size_t)64*SLEN*16 + 4096);
  unsigned short* lo_bf = (unsigned short*)take((size_t)MROWS*DMODEL*2);
  float* Sseg = (float*)take((size_t)64*NSEG*64*4);
  float4* pairb = (float4*)take((size_t)64*NGRP*4*16 + 4096);
  float* attn = Ab;  // safe alias: Ab consumed by kden before gemm2 writes attn

  cast_bf16_kernel<<<2048, 256, 0, stream>>>(h,     h_bf,  MROWS*DMODEL/4);
  cast_bf16_kernel<<<1024, 256, 0, stream>>>(wqkvb, wq_bf, NQKVB*DMODEL/4);
  cast_bf16_kernel<<<512,  256, 0, stream>>>(wo,    wo_bf, DMODEL*DMODEL/4);

  gemm_big_kernel<true><<<dim3(MROWS/128, NQPAD/128), 256, 0, stream>>>(
      h_bf, wq_bf, qkvb_bf, MROWS, NQPAD, DMODEL);

  prep_kernel<<<MROWS*NHEAD/4, 256, 0, stream>>>(qkvb_bf, qb, kb, vb, scal);
  segsum_kernel<<<dim3(64, NSEG), 64, 0, stream>>>(kb, Sseg);
  scan_kernel<<<dim3(64, NSEG), 64, 0, stream>>>(kb, Sseg, Ab);
  kden_kernel<<<64*SLEN/4, 256, 0, stream>>>(Ab, kb, qb, scal);
  pairdot_kernel<<<64*NGRP/4, 256, 0, stream>>>(kb, qb, pairb);
  recur_kernel<<<dim3(64, 16), 64, 0, stream>>>(kb, qb, vb, scal, pairb, lo_bf);

  gemm_big_kernel<false><<<dim3(MROWS/128, DMODEL/128), 256, 0, stream>>>(
      lo_bf, wo_bf, attn, MROWS, DMODEL, DMODEL);

  ln_kernel<<<MROWS, 256, 0, stream>>>(h, attn, lng, lnb, out);
  (void)in_sizes; (void)n_in; (void)out_size; (void)ws_size;
}